// Round 7
// baseline (1147.628 us; speedup 1.0000x reference)
//
#include <hip/hip_runtime.h>
#include <cmath>

// Volume: [B=4, C=1, D=128, H=128, W=128] fp32
#define NB 4
#define ND 128
#define NH 128
#define NW 128
#define NVOL_VOX (ND * NH * NW)    // 2097152 per volume
#define NVOX (NB * NVOL_VOX)       // 8388608 (4 volumes)

#define THREADS 256
#define TX 32
#define TY 16
// f4 frame stride 17 (68 floats == 4 mod 32) -> uniform bank-start for b128
#define SSTR 17
#define RSTR 9
#define ZS4 ((NH * NW) >> 2)       // 4096 f4 per z-slice

__device__ __forceinline__ float4 f4min(float4 a, float4 b) {
    return make_float4(fminf(a.x, b.x), fminf(a.y, b.y), fminf(a.z, b.z), fminf(a.w, b.w));
}
__device__ __forceinline__ float4 f4max(float4 a, float4 b) {
    return make_float4(fmaxf(a.x, b.x), fmaxf(a.y, b.y), fmaxf(a.z, b.z), fmaxf(a.w, b.w));
}
__device__ __forceinline__ float4 f4relu_sub(float4 a, float4 b) {
    return make_float4(fmaxf(a.x - b.x, 0.f), fmaxf(a.y - b.y, 0.f),
                       fmaxf(a.z - b.z, 0.f), fmaxf(a.w - b.w, 0.f));
}
__device__ __forceinline__ float4 f4winmin(float4 lf, float4 cc, float4 rt) {
    float4 o;
    o.x = fminf(fminf(lf.w, cc.x), cc.y);
    o.y = fminf(fminf(cc.x, cc.y), cc.z);
    o.z = fminf(fminf(cc.y, cc.z), cc.w);
    o.w = fminf(fminf(cc.z, cc.w), rt.x);
    return o;
}
__device__ __forceinline__ float4 f4winmax(float4 lf, float4 cc, float4 rt) {
    float4 o;
    o.x = fmaxf(fmaxf(lf.w, cc.x), cc.y);
    o.y = fmaxf(fmaxf(cc.x, cc.y), cc.z);
    o.z = fmaxf(fmaxf(cc.y, cc.z), cc.w);
    o.w = fmaxf(fmaxf(cc.z, cc.w), rt.x);
    return o;
}

__device__ __forceinline__ float block_reduce(float v, float* sbuf) {
    for (int off = 32; off > 0; off >>= 1) v += __shfl_down(v, off, 64);
    int lane = threadIdx.x & 63;
    int wid  = threadIdx.x >> 6;
    if (lane == 0) sbuf[wid] = v;
    __syncthreads();
    float r = 0.f;
    if (wid == 0) {
        r = (lane < (int)(blockDim.x >> 6)) ? sbuf[lane] : 0.f;
        for (int off = 8; off > 0; off >>= 1) r += __shfl_down(r, off, 64);
    }
    __syncthreads();
    return r;
}

// ---------------------------------------------------------------------------
// sigmoid + dice partials
// ---------------------------------------------------------------------------
#define SIG_BLOCKS 1024
__global__ void sigmoid_reduce_kernel(const float4* __restrict__ logits,
                                      const float4* __restrict__ yt,
                                      float4* __restrict__ yp,
                                      float* __restrict__ part) {
    __shared__ float sbuf[THREADS / 64];
    const int n4 = NVOX / 4;
    float sp = 0.f, st = 0.f, stp = 0.f;
    for (int i = blockIdx.x * blockDim.x + threadIdx.x; i < n4;
         i += gridDim.x * blockDim.x) {
        float4 l = logits[i];
        float4 t = yt[i];
        float4 p;
        p.x = 1.f / (1.f + expf(-l.x));
        p.y = 1.f / (1.f + expf(-l.y));
        p.z = 1.f / (1.f + expf(-l.z));
        p.w = 1.f / (1.f + expf(-l.w));
        yp[i] = p;
        sp  += p.x + p.y + p.z + p.w;
        st  += t.x + t.y + t.z + t.w;
        stp += t.x * p.x + t.y * p.y + t.z * p.z + t.w * p.w;
    }
    float a = block_reduce(sp, sbuf);
    float b = block_reduce(st, sbuf);
    float c = block_reduce(stp, sbuf);
    if (threadIdx.x == 0) {
        part[blockIdx.x]        = a;
        part[1024 + blockIdx.x] = b;
        part[2048 + blockIdx.x] = c;
    }
}

// ---------------------------------------------------------------------------
// Init step, single-slot frames, 2 barriers/z-step:
//   skel = relu(src - dilate(erode(src)))
// ---------------------------------------------------------------------------
__global__ __launch_bounds__(256, 4)
void init_step_kernel(const float* __restrict__ srcA, const float* __restrict__ srcB,
                      float* __restrict__ skel, int zchunks) {
    __shared__ float4 srcS[22 * SSTR];
    __shared__ float4 e1S [20 * SSTR];
    __shared__ float4 rxS [18 * RSTR];

    const float4 INF4  = make_float4(INFINITY, INFINITY, INFINITY, INFINITY);
    const float4 MINF4 = make_float4(-INFINITY, -INFINITY, -INFINITY, -INFINITY);

    const int zlen  = ND / zchunks;
    const int v     = blockIdx.z / zchunks;
    const int chunk = blockIdx.z - v * zchunks;
    const int z0    = chunk * zlen;
    const int tx0   = blockIdx.x * TX;
    const int ty0   = blockIdx.y * TY;
    const int tid   = threadIdx.x;

    const float* src = srcB ? (v < 4 ? srcA + (size_t)v * NVOL_VOX
                                     : srcB + (size_t)(v - 4) * NVOL_VOX)
                            : srcA + (size_t)v * NVOL_VOX;
    const float4* src4 = (const float4*)src;
    float4* skl4 = (float4*)(skel + (size_t)v * NVOL_VOX);

    const int fy = tid / 10, qx = tid - (tid / 10) * 10;
    const bool tOK = tid < 220;
    const bool aE1 = tOK && fy >= 1 && fy < 21;
    const bool aRx = tOK && fy >= 2 && fy < 20 && qx >= 1 && qx < 9;
    const bool aC  = tOK && fy >= 3 && fy < 19 && qx >= 1 && qx < 9;
    const int gy = ty0 + fy - 3;
    const int gx4 = tx0 + (qx - 1) * 4;
    const bool gOK = tOK && (unsigned)gy < NH && (unsigned)gx4 < NW;
    const int colBase = gOK ? ((gy * NW + gx4) >> 2) : 0;
    const int iSrc = fy * SSTR + qx + 1;
    const int iE1  = (fy - 1) * SSTR + qx + 1;
    const int iRx  = (fy - 2) * RSTR + (qx - 1);

    // guards: cols 0 and 11 of the min-frames
    for (int l = tid; l < 22 * 2; l += THREADS) srcS[(l >> 1) * SSTR + (l & 1) * 11] = INF4;
    for (int l = tid; l < 20 * 2; l += THREADS) e1S[(l >> 1) * SSTR + (l & 1) * 11] = INF4;
    __syncthreads();

    float4 srcF[6], e1F[2], rxF[2], mxyF[3];
#pragma unroll
    for (int i = 0; i < 6; ++i) srcF[i] = INF4;
    e1F[0] = e1F[1] = INF4;
    rxF[0] = rxF[1] = MINF4;
    mxyF[0] = mxyF[1] = mxyF[2] = MINF4;

    const int NSTEP = zlen + 8;
    for (int sb = 0; sb < NSTEP; sb += 6) {
#pragma unroll
        for (int u = 0; u < 6; ++u) {
            const int zL = z0 - 3 + (sb + u);

            // ======== READ + COMPUTE phase ========
            {   // L(zL)
                float4 vv = INF4;
                if ((unsigned)zL < ND && zL < z0 + zlen + 3 && gOK)
                    vv = src4[zL * ZS4 + colBase];
                srcF[u % 6] = vv;
            }
            {   // e1(zL-1): srcS holds src(zL-1)
                const int z = zL - 1;
                float4 vv = INF4;
                if (aE1 && (unsigned)z < ND) {
                    float4 xm = f4winmin(srcS[iSrc - 1], srcF[(u + 5) % 6], srcS[iSrc + 1]);
                    vv = f4min(f4min(xm, srcS[iSrc - SSTR]),
                               f4min(srcS[iSrc + SSTR],
                                     f4min(srcF[(u + 4) % 6], srcF[u % 6])));
                }
                e1F[u % 2] = vv;
            }
            {   // rx(zL-2) = max3x(e1(zL-2)): e1S holds e1(zL-2)
                float4 rxv = MINF4;
                if (aRx)
                    rxv = f4winmax(e1S[iE1 - 1], e1F[(u + 1) % 2], e1S[iE1 + 1]);
                // mxy(zL-3) = max3y(rx(zL-3)): rxS holds rx(zL-3)
                float4 m = MINF4;
                if (aC)
                    m = f4max(f4max(rxF[(u + 1) % 2], rxS[iRx - RSTR]),
                              rxS[iRx + RSTR]);
                rxF[u % 2] = rxv;
                mxyF[u % 3] = m;
            }
            {   // OUT(zL-4): skel = relu(src - dil)
                const int z = zL - 4;
                if (aC && z >= z0 && z < z0 + zlen) {
                    float4 dil = f4max(f4max(mxyF[0], mxyF[1]), mxyF[2]);
                    skl4[z * ZS4 + colBase] = f4relu_sub(srcF[(u + 2) % 6], dil);
                }
            }
            __syncthreads();

            // ======== WRITE phase ========
            if (tOK) srcS[iSrc] = srcF[u % 6];
            if (aE1) e1S[iE1]  = e1F[u % 2];
            if (aRx) rxS[iRx]  = rxF[u % 2];
            __syncthreads();
        }
    }
}

// ---------------------------------------------------------------------------
// Fused PAIR of skeleton iterations, single-slot frames, 2 barriers/z-step.
//   E1 = erode(src); E2 = erode(E1) [img out]; E3 = erode(E2)
//   dA = relu(E1 - dilate(E2));  dB = relu(E2 - dilate(E3))
//   s1 = s + relu(dA - s*dA); s2 = s1 + relu(dB - s1*dB)
// ---------------------------------------------------------------------------
template <int RED>
__global__ __launch_bounds__(256, 4)
void skel_pair_kernel(const float* __restrict__ srcA, const float* __restrict__ srcB,
                      float* __restrict__ imgOut, float* __restrict__ skel,
                      int zchunks,
                      const float* __restrict__ othA, const float* __restrict__ othB,
                      float* __restrict__ part, int offBase) {
    __shared__ float4 srcS[24 * SSTR];
    __shared__ float4 e1S [22 * SSTR];
    __shared__ float4 e2S [20 * SSTR];
    __shared__ float4 e3S [18 * SSTR];
    __shared__ float4 rxAS[18 * RSTR];
    __shared__ float4 rxBS[18 * RSTR];

    const float4 INF4  = make_float4(INFINITY, INFINITY, INFINITY, INFINITY);
    const float4 MINF4 = make_float4(-INFINITY, -INFINITY, -INFINITY, -INFINITY);

    const int zlen  = ND / zchunks;
    const int v     = blockIdx.z / zchunks;
    const int chunk = blockIdx.z - v * zchunks;
    const int z0    = chunk * zlen;
    const int tx0   = blockIdx.x * TX;
    const int ty0   = blockIdx.y * TY;
    const int tid   = threadIdx.x;

    const float* src = srcB ? (v < 4 ? srcA + (size_t)v * NVOL_VOX
                                     : srcB + (size_t)(v - 4) * NVOL_VOX)
                            : srcA + (size_t)v * NVOL_VOX;
    const float4* src4 = (const float4*)src;
    float4* img4 = imgOut ? (float4*)(imgOut + (size_t)v * NVOL_VOX) : nullptr;
    float4* skl4 = (float4*)(skel + (size_t)v * NVOL_VOX);
    const float4* oth4 = nullptr;
    if (RED) {
        const float* oth = othB ? (v < 4 ? othA + (size_t)v * NVOL_VOX
                                         : othB + (size_t)(v - 4) * NVOL_VOX)
                                : othA + (size_t)v * NVOL_VOX;
        oth4 = (const float4*)oth;
    }

    const int fy = tid / 10, qx = tid - (tid / 10) * 10;   // rows 0..23
    const bool tOK = tid < 240;
    const bool aE1 = tOK && fy >= 1 && fy < 23;
    const bool aE2 = tOK && fy >= 2 && fy < 22;
    const bool aE3 = tOK && fy >= 3 && fy < 21;
    const bool aRx = aE3 && qx >= 1 && qx < 9;
    const bool aC  = tOK && fy >= 4 && fy < 20 && qx >= 1 && qx < 9;
    const int gy = ty0 + fy - 4;
    const int gx4 = tx0 + (qx - 1) * 4;
    const bool gOK = tOK && (unsigned)gy < NH && (unsigned)gx4 < NW;
    const int colBase = gOK ? ((gy * NW + gx4) >> 2) : 0;
    const int iSrc = fy * SSTR + qx + 1;
    const int iE1  = (fy - 1) * SSTR + qx + 1;
    const int iE2  = (fy - 2) * SSTR + qx + 1;
    const int iE3  = (fy - 3) * SSTR + qx + 1;
    const int iRx  = (fy - 3) * RSTR + (qx - 1);

    // guards: cols 0 and 11
    for (int l = tid; l < 24 * 2; l += THREADS) srcS[(l >> 1) * SSTR + (l & 1) * 11] = INF4;
    for (int l = tid; l < 22 * 2; l += THREADS) e1S[(l >> 1) * SSTR + (l & 1) * 11] = INF4;
    for (int l = tid; l < 20 * 2; l += THREADS) e2S[(l >> 1) * SSTR + (l & 1) * 11] = INF4;
    for (int l = tid; l < 18 * 2; l += THREADS) e3S[(l >> 1) * SSTR + (l & 1) * 11] = INF4;
    __syncthreads();

    float4 srcF[3], e1F[6], e2F[6], e3F[2], rxAF[2], rxBF[2], mxyAF[3], mxyBF[3], dAF[2];
#pragma unroll
    for (int i = 0; i < 3; ++i) srcF[i] = INF4;
#pragma unroll
    for (int i = 0; i < 6; ++i) { e1F[i] = INF4; e2F[i] = INF4; }
    e3F[0] = e3F[1] = INF4;
    rxAF[0] = rxAF[1] = MINF4;
    rxBF[0] = rxBF[1] = MINF4;
    mxyAF[0] = mxyAF[1] = mxyAF[2] = MINF4;
    mxyBF[0] = mxyBF[1] = mxyBF[2] = MINF4;
    dAF[0] = dAF[1] = make_float4(0.f, 0.f, 0.f, 0.f);

    float accS = 0.f, accSO = 0.f;
    const int NSTEP = zlen + 10;

    for (int sb = 0; sb < NSTEP; sb += 6) {
#pragma unroll
        for (int u = 0; u < 6; ++u) {
            const int zL = z0 - 4 + (sb + u);

            // ======== READ + COMPUTE phase ========
            {   // L(zL)
                float4 vv = INF4;
                if ((unsigned)zL < ND && zL < z0 + zlen + 4 && gOK)
                    vv = src4[zL * ZS4 + colBase];
                srcF[u % 3] = vv;
            }
            {   // E1(zL-1): srcS holds src(zL-1)
                const int z = zL - 1;
                float4 vv = INF4;
                if (aE1 && (unsigned)z < ND) {
                    float4 xm = f4winmin(srcS[iSrc - 1], srcF[(u + 2) % 3], srcS[iSrc + 1]);
                    vv = f4min(f4min(xm, srcS[iSrc - SSTR]),
                               f4min(srcS[iSrc + SSTR],
                                     f4min(srcF[(u + 1) % 3], srcF[u % 3])));
                }
                e1F[u % 6] = vv;
            }
            {   // E2(zL-2): e1S holds e1(zL-2); img out
                const int z = zL - 2;
                float4 vv = INF4;
                if (aE2) {
                    float4 xm = f4winmin(e1S[iE1 - 1], e1F[(u + 5) % 6], e1S[iE1 + 1]);
                    vv = f4min(f4min(xm, e1S[iE1 - SSTR]),
                               f4min(e1S[iE1 + SSTR],
                                     f4min(e1F[(u + 4) % 6], e1F[u % 6])));
                    if (img4 && aC && z >= z0 && z < z0 + zlen)
                        img4[z * ZS4 + colBase] = vv;
                }
                e2F[u % 6] = vv;
            }
            {   // E3(zL-3): e2S holds e2(zL-3)
                float4 vv = INF4;
                if (aE3) {
                    float4 xm = f4winmin(e2S[iE2 - 1], e2F[(u + 5) % 6], e2S[iE2 + 1]);
                    vv = f4min(f4min(xm, e2S[iE2 - SSTR]),
                               f4min(e2S[iE2 + SSTR],
                                     f4min(e2F[(u + 4) % 6], e2F[u % 6])));
                }
                e3F[u % 2] = vv;
            }
            {   // rxA(zL-3) from e2S; rxB(zL-4) from e3S (holds e3(zL-4))
                float4 ra = MINF4, rb = MINF4;
                if (aRx) {
                    ra = f4winmax(e2S[iE2 - 1], e2F[(u + 5) % 6], e2S[iE2 + 1]);
                    rb = f4winmax(e3S[iE3 - 1], e3F[(u + 1) % 2], e3S[iE3 + 1]);
                }
                // mxyA(zL-4), mxyB(zL-5): rx frames hold rx(zL-4)/rx(zL-5)
                float4 mA = MINF4, mB = MINF4;
                if (aC) {
                    mA = f4max(f4max(rxAF[(u + 1) % 2], rxAS[iRx - RSTR]),
                               rxAS[iRx + RSTR]);
                    mB = f4max(f4max(rxBF[(u + 1) % 2], rxBS[iRx - RSTR]),
                               rxBS[iRx + RSTR]);
                }
                rxAF[u % 2] = ra;
                rxBF[u % 2] = rb;
                mxyAF[u % 3] = mA;
                mxyBF[u % 3] = mB;
            }
            {   // dA(zL-5) = relu(E1(zL-5) - dilA)
                float4 dilA = f4max(f4max(mxyAF[0], mxyAF[1]), mxyAF[2]);
                dAF[u % 2] = f4relu_sub(e1F[(u + 2) % 6], dilA);
            }
            {   // OUT(zL-6): apply dA then dB
                const int z = zL - 6;
                if (aC && z >= z0 && z < z0 + zlen) {
                    float4 dilB = f4max(f4max(mxyBF[0], mxyBF[1]), mxyBF[2]);
                    float4 dB = f4relu_sub(e2F[(u + 2) % 6], dilB);
                    float4 da = dAF[(u + 1) % 2];
                    int gi = z * ZS4 + colBase;
                    float4 sv = skl4[gi];
                    float4 s1, s2;
                    s1.x = sv.x + fmaxf(da.x - sv.x * da.x, 0.f);
                    s1.y = sv.y + fmaxf(da.y - sv.y * da.y, 0.f);
                    s1.z = sv.z + fmaxf(da.z - sv.z * da.z, 0.f);
                    s1.w = sv.w + fmaxf(da.w - sv.w * da.w, 0.f);
                    s2.x = s1.x + fmaxf(dB.x - s1.x * dB.x, 0.f);
                    s2.y = s1.y + fmaxf(dB.y - s1.y * dB.y, 0.f);
                    s2.z = s1.z + fmaxf(dB.z - s1.z * dB.z, 0.f);
                    s2.w = s1.w + fmaxf(dB.w - s1.w * dB.w, 0.f);
                    skl4[gi] = s2;
                    if (RED) {
                        accS += s2.x + s2.y + s2.z + s2.w;
                        float4 o = oth4[gi];
                        accSO += s2.x * o.x + s2.y * o.y + s2.z * o.z + s2.w * o.w;
                    }
                }
            }
            __syncthreads();

            // ======== WRITE phase ========
            if (tOK) srcS[iSrc] = srcF[u % 3];
            if (aE1) e1S[iE1]  = e1F[u % 6];
            if (aE2) e2S[iE2]  = e2F[u % 6];
            if (aE3) e3S[iE3]  = e3F[u % 2];
            if (aRx) { rxAS[iRx] = rxAF[u % 2]; rxBS[iRx] = rxBF[u % 2]; }
            __syncthreads();
        }
    }

    if (RED) {
        float* sbuf = (float*)srcS;
        float r1 = block_reduce(accS, sbuf);
        float r2 = block_reduce(accSO, sbuf);
        if (tid == 0) {
            int halfSel = (othB && v >= 4) ? 1 : 0;
            int A = (offBase + 2 * halfSel) * 1024;
            int zslot = chunk + zchunks * (v & 3);
            int bid = blockIdx.x + 4 * (blockIdx.y + 8 * zslot);
            part[A + bid] = r1;
            part[A + 1024 + bid] = r2;
        }
    }
}

// ---------------------------------------------------------------------------
// finalize: sum 7 partial arrays (1024 each) and compute the loss scalar
// ---------------------------------------------------------------------------
__global__ void finalize_kernel(const float* __restrict__ part, float* __restrict__ out) {
    __shared__ float sbuf[THREADS / 64];
    float s[7];
#pragma unroll
    for (int k = 0; k < 7; ++k) {
        float local = 0.f;
        for (int i = threadIdx.x; i < 1024; i += THREADS) local += part[k * 1024 + i];
        s[k] = block_reduce(local, sbuf);
    }
    if (threadIdx.x == 0) {
        const float smooth = 1.0f;
        const float alpha = 0.3f;
        float dice = 1.f - (2.f * s[2] + smooth) / (s[1] + s[0] + smooth);
        float tprec = (s[4] + smooth) / (s[3] + smooth);
        float tsens = (s[6] + smooth) / (s[5] + smooth);
        float cl = 1.f - 2.f * (tprec * tsens) / (tprec + tsens);
        out[0] = (1.f - alpha) * dice + alpha * cl;
    }
}

// ---------------------------------------------------------------------------
extern "C" void kernel_launch(void* const* d_in, const int* in_sizes, int n_in,
                              void* d_out, int out_size, void* d_ws, size_t ws_size,
                              hipStream_t stream) {
    const float* y_pred = (const float*)d_in[0];
    const float* y_true = (const float*)d_in[1];
    float* out = (float*)d_out;

    char* ws = (char*)d_ws;
    float* part = (float*)ws;                 // 7 * 1024 floats
    float* yp = (float*)(ws + 32768);
    const size_t NB4 = (size_t)NVOX;
    const size_t need_batched = 32768 + 7 * NB4 * sizeof(float);

    hipMemsetAsync(part, 0, 7 * 1024 * sizeof(float), stream);
    sigmoid_reduce_kernel<<<SIG_BLOCKS, THREADS, 0, stream>>>(
        (const float4*)y_pred, (const float4*)y_true, (float4*)yp, part);

    if (ws_size >= need_batched) {
        // batched: both skeletons (8 volumes) per dispatch
        float* ping = yp + NB4;          // 8-vol
        float* pong = ping + 2 * NB4;    // 8-vol
        float* S    = pong + 2 * NB4;    // 8-vol
        const int zc = 4;                // zlen 32
        dim3 grid(NW / TX, NH / TY, zc * 8);

        init_step_kernel<<<grid, THREADS, 0, stream>>>(yp, y_true, S, zc);

        float* bufs[2] = {ping, pong};
        for (int i = 0; i < 8; ++i) {
            const float* sA = (i == 0) ? yp : bufs[(i + 1) & 1];
            const float* sB = (i == 0) ? y_true : nullptr;
            float* oimg = (i < 7) ? bufs[i & 1] : nullptr;   // last pair: img dead
            if (i < 7)
                skel_pair_kernel<0><<<grid, THREADS, 0, stream>>>(
                    sA, sB, oimg, S, zc, nullptr, nullptr, nullptr, 0);
            else
                skel_pair_kernel<1><<<grid, THREADS, 0, stream>>>(
                    sA, sB, oimg, S, zc, y_true, yp, part, 3);
        }
    } else {
        // sequential fallback: one skeleton stream (4 vols) at a time
        float* ping = yp + NB4;
        float* pong = ping + NB4;
        float* Sp   = pong + NB4;
        float* St   = Sp + NB4;
        const int zc = 8;                // zlen 16
        dim3 grid(NW / TX, NH / TY, zc * 4);

        auto run = [&](const float* x, float* S, const float* other, int offBase) {
            init_step_kernel<<<grid, THREADS, 0, stream>>>(x, nullptr, S, zc);
            float* bufs[2] = {ping, pong};
            for (int i = 0; i < 8; ++i) {
                const float* sA = (i == 0) ? x : bufs[(i + 1) & 1];
                float* oimg = (i < 7) ? bufs[i & 1] : nullptr;
                if (i < 7)
                    skel_pair_kernel<0><<<grid, THREADS, 0, stream>>>(
                        sA, nullptr, oimg, S, zc, nullptr, nullptr, nullptr, 0);
                else
                    skel_pair_kernel<1><<<grid, THREADS, 0, stream>>>(
                        sA, nullptr, oimg, S, zc, other, nullptr, part, offBase);
            }
        };
        run(yp, Sp, y_true, 3);
        run(y_true, St, yp, 5);
    }

    finalize_kernel<<<1, THREADS, 0, stream>>>(part, out);
}